// Round 1
// baseline (137.438 us; speedup 1.0000x reference)
//
#include <hip/hip_runtime.h>
#include <cstddef>
#include <cstdint>

// B=256, N=32, F=40, H=M=100, EF=4, OUT=128, 3 passes.
#define B_   256
#define N_   32
#define F_   40
#define H_   100
#define OUT_ 128
#define TB   1024         // 16 waves/block -> 4 waves/SIMD, 1 block/CU
#define XCS  168          // XcH row stride (shorts), 16B-multiple
#define XMS  136          // Xy row stride (shorts), 16B-multiple
#define ST2  40           // XcT row stride (shorts): [k][g], 16B-multiple
#define NBLK 483          // AFhi blocks: 336 P(=Wih@Wmsg_t) + 84 hh + 35 Wg + 28 We
#define NLO  63           // AFlo blocks (readout lo)

using bf16x8 = __attribute__((ext_vector_type(8))) short;   // 8 bf16 (4 VGPRs)
using f32x4  = __attribute__((ext_vector_type(4))) float;   // MFMA C/D

#define MFMA(a,b,c) __builtin_amdgcn_mfma_f32_16x16x32_bf16((a),(b),(c),0,0,0)

__device__ __forceinline__ float sigmoidf_(float x){ return 1.0f/(1.0f+__expf(-x)); }
__device__ __forceinline__ float tanhf_(float x){           // fast tanh via __expf
  float e = __expf(2.0f*x);
  return 1.0f - 2.0f/(e+1.0f);
}
__device__ __forceinline__ float bf2f(short s){ return __uint_as_float(((uint32_t)(uint16_t)s)<<16); }
__device__ __forceinline__ short f2bf(float x){             // round-to-nearest-even
  uint32_t u = __float_as_uint(x);
  return (short)((u + 0x7FFFu + ((u>>16)&1u))>>16);
}
__device__ __forceinline__ void bsplit(float x, short& hi, short& lo){
  hi = f2bf(x);
  lo = f2bf(x - bf2f(hi));
}

// ---------------------------------------------------------------------------
// Weight pre-pack v5: SLOT-indexed, OOR slots get 0.
//   [0,336)   P_t^mat = W_ih_mat @ W_msg_t : (mat*4+t)*28 + jmt*4 + ks
//             A[j][h] = sum_m W_ih[mat*100+j][m] * W_msg[m,h,t]   (K-dim = h)
//   [336,420) hh GRU  : 336 + mat*28 + jmt*4 + ks   A[j][k] = W_hh[mat*100+j][k]
//   [420,455) Wg^T    : 420 + jmt*5 + ks (K=140)    A[j][k] = Wg[k, j]  (hi+lo)
//   [455,483) We^T    : 455 + jmt*4 + ks            A[j][k] = We[k, j]  (hi+lo)
// The msg stage is folded into ih: gi = Sum_t P_t Y_t (exact linear identity),
// which removes one barrier-region per pass and the Xm bf16 rounding stage.
// ---------------------------------------------------------------------------
__global__ void prep_frags5(const float* __restrict__ Wmsg,
                            const float* __restrict__ Wih,
                            const float* __restrict__ Whh,
                            const float* __restrict__ Wg,
                            const float* __restrict__ We,
                            short* __restrict__ AFhi,
                            short* __restrict__ AFlo){
  int slot = blockIdx.x*blockDim.x + threadIdx.x;
  if (slot >= NBLK*512) return;
  int blk = slot>>9, r = slot&511, lane = r>>3, jj = r&7;
  int m = lane&15, q = lane>>4, kl = q*8+jj;
  float v = 0.0f;
  if (blk < 336){                                  // fused P blocks
    int mt = blk/28, rem = blk%28, jmt = rem>>2, ks = rem&3;
    int mat = mt>>2, t = mt&3;
    int rr = jmt*16+m, h = ks*32+kl;
    if (rr<100 && h<100){
      const float* wih = Wih + ((size_t)(mat*100+rr))*100;   // row, stride 1
      const float* wm  = Wmsg + (size_t)h*4 + t;             // col, stride 400
      float s = 0.0f;
#pragma unroll 4
      for (int mp=0; mp<100; ++mp) s += wih[mp]*wm[(size_t)mp*400];
      v = s;
    }
    AFhi[slot] = f2bf(v);
  } else if (blk < 420){                           // hh gates
    int bb = blk-336, mat = bb/28, rem = bb%28, jmt = rem>>2, ks = rem&3;
    int mg = jmt*16+m, k = ks*32+kl;
    if (mg<100 && k<100) v = Whh[((size_t)(mat*100+mg))*100+k];
    AFhi[slot] = f2bf(v);
  } else if (blk < 455){                           // Wg^T hi+lo
    int bb = blk-420, jmt = bb/5, ks = bb%5;
    int mg = jmt*16+m, k = ks*32+kl;
    if (mg<100 && k<140) v = Wg[(size_t)k*100+mg];
    short hi,lo; bsplit(v,hi,lo);
    AFhi[slot] = hi;
    AFlo[(size_t)(blk-420)*512 + r] = lo;
  } else {                                         // We^T hi+lo
    int bb = blk-455, jmt = bb>>2, ks = bb&3;
    int mg = jmt*16+m, k = ks*32+kl;
    if (mg<100 && k<100) v = We[(size_t)k*100+mg];
    short hi,lo; bsplit(v,hi,lo);
    AFhi[slot] = hi;
    AFlo[(size_t)(blk-420)*512 + r] = lo;
  }
}

// ---------------------------------------------------------------------------
// Fused MPNN. 14 tile-tasks (jmt<7 x nt<2), one per wave. 2 barriers/pass:
//  [Y-agg (4 MFMA, short4 C-writes) + hh gates (12 MFMA, B shared)] bar
//  [ih gates = Sum_t P_t Y_t (48 MFMA) + GRU elementwise (reg h-state)] bar
// h-state: task map is pass-invariant, so each lane owns its 4 GRU cells in
// fp32 registers across passes. Node mask via __ballot (no LDS atomics).
// ---------------------------------------------------------------------------
__global__ __launch_bounds__(TB, 4) void mpnn_mfma(
    const float* __restrict__ nodes, const float* __restrict__ edges,
    const short* __restrict__ AFhi, const short* __restrict__ AFlo,
    const float* __restrict__ b_ih, const float* __restrict__ b_hh,
    const float* __restrict__ bg, const float* __restrict__ be,
    const float* __restrict__ Wo, const float* __restrict__ bo,
    float* __restrict__ out){
  const int b = blockIdx.x;
  const int tid = threadIdx.x;
  const int lane = tid & 63;
  const int w = tid >> 6;

  __shared__ short XcH[32*XCS];                   // cat: h | nodes(100..139) | 0
  __shared__ short XcT[112*ST2];                  // transposed h [k][g]
  __shared__ short XyH[4][32*XMS];                // per-type Y_t (bf16) [n][k]
  __shared__ short Aw[4][32*32];                  // adjacency [t][n][g] (bf16)
  __shared__ float sh_ge[H_];
  __shared__ float sh_part[4][OUT_];              // Wo-tail partials
  __shared__ int   sh_msk[N_];                    // node-has-edges mask

  // ---- zero LDS (rows never written later must be 0) -----------------------
  for (int i=tid;i<(32*XCS)/2;i+=TB){ ((int*)XcH)[i]=0; }
  for (int i=tid;i<(112*ST2)/2;i+=TB){ ((int*)XcT)[i]=0; }
  for (int i=tid;i<(4*32*XMS)/2;i+=TB){ ((int*)XyH)[i]=0; }
  if (tid < H_) sh_ge[tid]=0.0f;
  __syncthreads();

  // ---- edge staging: adjacency planes + ballot mask (tid == (n,g), TB==N*N)
  {
    int n = tid>>5, g = tid&31;
    const float4 ev = *(const float4*)(edges + (((size_t)b*N_+n)*N_+g)*4);
    float adj = ev.x+ev.y+ev.z+ev.w;                 // one-hot sums, >=0
    unsigned long long bal = __ballot(adj != 0.0f);  // wave covers rows 2w,2w+1
    if (lane == 0)  sh_msk[n] = ((int)(bal & 0xFFFFFFFFull)) != 0;
    if (lane == 32) sh_msk[n] = ((int)(bal >> 32)) != 0;
    Aw[0][n*32+g] = f2bf(ev.x);
    Aw[1][n*32+g] = f2bf(ev.y);
    Aw[2][n*32+g] = f2bf(ev.z);
    Aw[3][n*32+g] = f2bf(ev.w);
  }
  for (int p=tid; p<N_*F_; p+=TB){              // grid-stride: 1280 > TB
    int n = p/F_, f = p%F_;
    float x = nodes[((size_t)b*N_+n)*F_ + f];
    short hi = f2bf(x);
    XcH[n*XCS+f]=hi;                            // h init rows 0..39
    XcH[n*XCS+100+f]=hi;                        // cat-tail rows 100..139
    XcT[f*ST2+n]=hi;                            // transposed h init
  }

  const int jmt = w>>1, nt = w&1;               // task (w<14)
  const bool task = (w < 14);
  const int nrow = nt*16 + (lane&15);           // this lane's B-row (node)
  const int boff = (lane>>4)*8;                 // this lane's k-offset in frag
  const int rowbase = jmt*16 + (lane>>4)*4;     // this lane's 4 output rows

  // ---- per-lane fp32 GRU state (pass-invariant cell ownership) -------------
  float hst[4] = {0.f,0.f,0.f,0.f};
  if (task){
#pragma unroll
    for (int r=0;r<4;++r){
      int row = rowbase + r;
      if (row < F_) hst[r] = nodes[((size_t)b*N_+nrow)*F_ + row];
    }
  }
  __syncthreads();

  for (int pass=0; pass<3; ++pass){
    // ---- region 0: Y-agg (4 MFMA, short4 writes) + hh gates (B shared) -----
    f32x4 Ch0=(f32x4)0.0f, Ch1=(f32x4)0.0f, Ch2=(f32x4)0.0f;
    if (task){
      {
        bf16x8 at = *(const bf16x8*)&XcT[(jmt*16+(lane&15))*ST2 + boff];
        int kbase = jmt*16 + (boff>>1);         // = jmt*16 + quad*4
#pragma unroll
        for (int t=0;t<4;++t){
          bf16x8 bt = *(const bf16x8*)&Aw[t][nrow*32 + boff];
          f32x4 D = (f32x4)0.0f;
          D = MFMA(at, bt, D);
          short4 pk;                             // 4 contiguous k -> one b64
          pk.x = f2bf(D[0]); pk.y = f2bf(D[1]);
          pk.z = f2bf(D[2]); pk.w = f2bf(D[3]);
          *(short4*)&XyH[t][nrow*XMS + kbase] = pk;
        }
      }
      {  // hh gates: load XcH B-frags ONCE, reuse for 3 gates
        const short* pb = XcH + nrow*XCS + boff;
        bf16x8 b0 = *(const bf16x8*)(pb);
        bf16x8 b1 = *(const bf16x8*)(pb+32);
        bf16x8 b2 = *(const bf16x8*)(pb+64);
        bf16x8 b3 = *(const bf16x8*)(pb+96);
        const short* pa = AFhi + ((size_t)(336 + jmt*4))*512 + lane*8;
        {
          bf16x8 a0=*(const bf16x8*)(pa),      a1=*(const bf16x8*)(pa+512);
          bf16x8 a2=*(const bf16x8*)(pa+1024), a3=*(const bf16x8*)(pa+1536);
          Ch0 = MFMA(a0,b0,Ch0); Ch0 = MFMA(a1,b1,Ch0);
          Ch0 = MFMA(a2,b2,Ch0); Ch0 = MFMA(a3,b3,Ch0);
        }
        pa += 28*512;
        {
          bf16x8 a0=*(const bf16x8*)(pa),      a1=*(const bf16x8*)(pa+512);
          bf16x8 a2=*(const bf16x8*)(pa+1024), a3=*(const bf16x8*)(pa+1536);
          Ch1 = MFMA(a0,b0,Ch1); Ch1 = MFMA(a1,b1,Ch1);
          Ch1 = MFMA(a2,b2,Ch1); Ch1 = MFMA(a3,b3,Ch1);
        }
        pa += 28*512;
        {
          bf16x8 a0=*(const bf16x8*)(pa),      a1=*(const bf16x8*)(pa+512);
          bf16x8 a2=*(const bf16x8*)(pa+1024), a3=*(const bf16x8*)(pa+1536);
          Ch2 = MFMA(a0,b0,Ch2); Ch2 = MFMA(a1,b1,Ch2);
          Ch2 = MFMA(a2,b2,Ch2); Ch2 = MFMA(a3,b3,Ch2);
        }
      }
    }
    __syncthreads();
    // ---- region 1: ih gates = Sum_t P_t Y_t (48 MFMA) + GRU (reg state) ----
    if (task){
      f32x4 Ci0=(f32x4)0.0f, Ci1=(f32x4)0.0f, Ci2=(f32x4)0.0f;
#pragma unroll 1
      for (int t=0;t<4;++t){
        const short* pb = XyH[t] + nrow*XMS + boff;
        bf16x8 b0 = *(const bf16x8*)(pb);
        bf16x8 b1 = *(const bf16x8*)(pb+32);
        bf16x8 b2 = *(const bf16x8*)(pb+64);
        bf16x8 b3 = *(const bf16x8*)(pb+96);
        const short* pa = AFhi + ((size_t)(t*28 + jmt*4))*512 + lane*8;
        {
          bf16x8 a0=*(const bf16x8*)(pa),      a1=*(const bf16x8*)(pa+512);
          bf16x8 a2=*(const bf16x8*)(pa+1024), a3=*(const bf16x8*)(pa+1536);
          Ci0 = MFMA(a0,b0,Ci0); Ci0 = MFMA(a1,b1,Ci0);
          Ci0 = MFMA(a2,b2,Ci0); Ci0 = MFMA(a3,b3,Ci0);
        }
        pa += 112*512;                          // mat stride = 4*28 blocks
        {
          bf16x8 a0=*(const bf16x8*)(pa),      a1=*(const bf16x8*)(pa+512);
          bf16x8 a2=*(const bf16x8*)(pa+1024), a3=*(const bf16x8*)(pa+1536);
          Ci1 = MFMA(a0,b0,Ci1); Ci1 = MFMA(a1,b1,Ci1);
          Ci1 = MFMA(a2,b2,Ci1); Ci1 = MFMA(a3,b3,Ci1);
        }
        pa += 112*512;
        {
          bf16x8 a0=*(const bf16x8*)(pa),      a1=*(const bf16x8*)(pa+512);
          bf16x8 a2=*(const bf16x8*)(pa+1024), a3=*(const bf16x8*)(pa+1536);
          Ci2 = MFMA(a0,b0,Ci2); Ci2 = MFMA(a1,b1,Ci2);
          Ci2 = MFMA(a2,b2,Ci2); Ci2 = MFMA(a3,b3,Ci2);
        }
      }
      if (rowbase < 100){                        // quads never straddle 100
        bool msk = sh_msk[nrow] != 0;
        short4 pk;
#pragma unroll
        for (int r=0;r<4;++r){
          int row = rowbase + r;
          float ho = hst[r];
          float rr = sigmoidf_(Ci0[r]+Ch0[r] + b_ih[row]     + b_hh[row]);
          float zz = sigmoidf_(Ci1[r]+Ch1[r] + b_ih[100+row] + b_hh[100+row]);
          float nn = tanhf_(Ci2[r] + b_ih[200+row] + rr*(Ch2[r] + b_hh[200+row]));
          float hnew = (1.0f-zz)*nn + zz*ho;
          if (!msk) hnew = ho;
          hst[r] = hnew;
          short hb = f2bf(hnew);
          ((short*)&pk)[r] = hb;
          XcT[row*ST2+nrow] = hb;               // transposed copy (scatter)
        }
        *(short4*)&XcH[nrow*XCS + rowbase] = pk;
      }
    }
    __syncthreads();
  }

  // ---- readout: gate/emb GEMMs (A hi+lo, B=XcH shared), masked sum ---------
  f32x4 Cg=(f32x4)0.0f, Ce=(f32x4)0.0f;
  if (task){
    const short* pb = XcH + nrow*XCS + boff;
    bf16x8 b0 = *(const bf16x8*)(pb);
    bf16x8 b1 = *(const bf16x8*)(pb+32);
    bf16x8 b2 = *(const bf16x8*)(pb+64);
    bf16x8 b3 = *(const bf16x8*)(pb+96);
    bf16x8 b4 = *(const bf16x8*)(pb+128);
    {  // Wg: blocks 420+jmt*5 .. +4 (hi) and same-idx lo
      const short* ph = AFhi + ((size_t)(420 + jmt*5))*512 + lane*8;
      const short* pl = AFlo + ((size_t)(jmt*5))*512 + lane*8;
      Cg = MFMA(*(const bf16x8*)(ph),      b0, Cg);
      Cg = MFMA(*(const bf16x8*)(pl),      b0, Cg);
      Cg = MFMA(*(const bf16x8*)(ph+512),  b1, Cg);
      Cg = MFMA(*(const bf16x8*)(pl+512),  b1, Cg);
      Cg = MFMA(*(const bf16x8*)(ph+1024), b2, Cg);
      Cg = MFMA(*(const bf16x8*)(pl+1024), b2, Cg);
      Cg = MFMA(*(const bf16x8*)(ph+1536), b3, Cg);
      Cg = MFMA(*(const bf16x8*)(pl+1536), b3, Cg);
      Cg = MFMA(*(const bf16x8*)(ph+2048), b4, Cg);
      Cg = MFMA(*(const bf16x8*)(pl+2048), b4, Cg);
    }
    {  // We: blocks 455+jmt*4 .. +3 (hi), lo at (blk-420)
      const short* ph = AFhi + ((size_t)(455 + jmt*4))*512 + lane*8;
      const short* pl = AFlo + ((size_t)(35 + jmt*4))*512 + lane*8;
      Ce = MFMA(*(const bf16x8*)(ph),      b0, Ce);
      Ce = MFMA(*(const bf16x8*)(pl),      b0, Ce);
      Ce = MFMA(*(const bf16x8*)(ph+512),  b1, Ce);
      Ce = MFMA(*(const bf16x8*)(pl+512),  b1, Ce);
      Ce = MFMA(*(const bf16x8*)(ph+1024), b2, Ce);
      Ce = MFMA(*(const bf16x8*)(pl+1024), b2, Ce);
      Ce = MFMA(*(const bf16x8*)(ph+1536), b3, Ce);
      Ce = MFMA(*(const bf16x8*)(pl+1536), b3, Ce);
    }
    bool msk = sh_msk[nrow] != 0;
#pragma unroll
    for (int r=0;r<4;++r){
      int row = rowbase + r;
      float v = 0.0f;
      if (row<100){
        float gate = sigmoidf_(Cg[r] + bg[row]);
        float emb  = gate*(Ce[r] + be[row]);
        v = msk ? emb : 0.0f;
      }
      v += __shfl_xor(v, 1);                   // reduce across 16 cols
      v += __shfl_xor(v, 2);
      v += __shfl_xor(v, 4);
      v += __shfl_xor(v, 8);
      if (row<100 && (lane&15)==0) atomicAdd(&sh_ge[row], v);
    }
  }
  __syncthreads();
  // ---- out = graph_emb @ Wo + bo : 512 threads, 4 k-chunks of 25 -----------
  if (tid < 512){
    int o = tid & 127, q = tid >> 7;           // lanes consecutive in o -> coalesced
    float s = 0.0f;
    int k0 = 25*q;
#pragma unroll 5
    for (int k=k0; k<k0+25; ++k) s += sh_ge[k]*Wo[k*OUT_+o];
    sh_part[q][o] = s;
  }
  __syncthreads();
  if (tid < OUT_){
    out[(size_t)b*OUT_ + tid] = bo[tid] + sh_part[0][tid] + sh_part[1][tid]
                              + sh_part[2][tid] + sh_part[3][tid];
  }
}

extern "C" void kernel_launch(void* const* d_in, const int* in_sizes, int n_in,
                              void* d_out, int out_size, void* d_ws, size_t ws_size,
                              hipStream_t stream){
  const float* nodes = (const float*)d_in[0];
  const float* edges = (const float*)d_in[1];
  const float* W_msg = (const float*)d_in[2];
  const float* W_ih  = (const float*)d_in[3];
  const float* W_hh  = (const float*)d_in[4];
  const float* b_ih  = (const float*)d_in[5];
  const float* b_hh  = (const float*)d_in[6];
  const float* Wg    = (const float*)d_in[7];
  const float* bg    = (const float*)d_in[8];
  const float* We    = (const float*)d_in[9];
  const float* be    = (const float*)d_in[10];
  const float* Wo    = (const float*)d_in[11];
  const float* bo    = (const float*)d_in[12];

  short* AFhi = (short*)d_ws;                        // 483*512 shorts = 483 KB
  short* AFlo = AFhi + (size_t)NBLK*512;             //  63*512 shorts =  63 KB

  prep_frags5<<<(NBLK*512 + 255)/256, 256, 0, stream>>>(W_msg, W_ih, W_hh, Wg, We,
                                                        AFhi, AFlo);
  mpnn_mfma<<<B_, TB, 0, stream>>>(nodes, edges, AFhi, AFlo, b_ih, b_hh, bg, be,
                                   Wo, bo, (float*)d_out);
}

// Round 2
// 123.007 us; speedup vs baseline: 1.1173x; 1.1173x over previous
//
#include <hip/hip_runtime.h>
#include <cstddef>
#include <cstdint>

// B=256, N=32, F=40, H=M=100, EF=4, OUT=128, 3 passes.
#define B_   256
#define N_   32
#define F_   40
#define H_   100
#define OUT_ 128
#define TB   1024         // 16 waves/block -> 4 waves/SIMD, 1 block/CU
#define XCS  168          // XcH row stride (shorts), 16B-multiple
#define XMS  136          // XmH row stride (shorts), 16B-multiple
#define AWS  40           // Aw row stride (shorts): pad 32->40 kills 8-way conflict
#define ZSP  40           // Zs row stride (shorts)
#define NBLK 343          // AFhi blocks: 112 msg + 168 GRU + 35 Wg + 28 We
#define NLO  63           // AFlo blocks (readout lo)

using bf16x8 = __attribute__((ext_vector_type(8))) short;   // 8 bf16 (4 VGPRs)
using f32x4  = __attribute__((ext_vector_type(4))) float;   // MFMA C/D

#define MFMA(a,b,c) __builtin_amdgcn_mfma_f32_16x16x32_bf16((a),(b),(c),0,0,0)

__device__ __forceinline__ float sigmoidf_(float x){ return 1.0f/(1.0f+__expf(-x)); }
__device__ __forceinline__ float tanhf_(float x){           // fast tanh via __expf
  float e = __expf(2.0f*x);
  return 1.0f - 2.0f/(e+1.0f);
}
__device__ __forceinline__ float bf2f(short s){ return __uint_as_float(((uint32_t)(uint16_t)s)<<16); }
__device__ __forceinline__ short f2bf(float x){             // round-to-nearest-even
  uint32_t u = __float_as_uint(x);
  return (short)((u + 0x7FFFu + ((u>>16)&1u))>>16);
}
__device__ __forceinline__ void bsplit(float x, short& hi, short& lo){
  hi = f2bf(x);
  lo = f2bf(x - bf2f(hi));
}

// ---------------------------------------------------------------------------
// Weight pre-pack v4 (proven trivial-copy layout): SLOT-indexed, OOR slots 0.
//   [0,112)   W_msg : t*28 + jmt*4 + ks        A[m][h]=W_msg[m, h, t]
//   [112,280) GRU   : 112+mat*28+jmt*4+ks      mat: ihr,ihz,ihn,hhr,hhz,hhn
//   [280,315) Wg^T  : 280+jmt*5+ks (K=140)     A[j][k]=Wg[k, j]  (hi+lo)
//   [315,343) We^T  : 315+jmt*4+ks             A[j][k]=We[k, j]  (hi+lo)
// ---------------------------------------------------------------------------
__global__ void prep_frags4(const float* __restrict__ Wmsg,
                            const float* __restrict__ Wih,
                            const float* __restrict__ Whh,
                            const float* __restrict__ Wg,
                            const float* __restrict__ We,
                            short* __restrict__ AFhi,
                            short* __restrict__ AFlo){
  int slot = blockIdx.x*blockDim.x + threadIdx.x;
  if (slot >= NBLK*512) return;
  int blk = slot>>9, r = slot&511, lane = r>>3, jj = r&7;
  int m = lane&15, q = lane>>4, kl = q*8+jj;
  float v = 0.0f;
  if (blk < 112){
    int t = blk/28, rem = blk%28, jmt = rem>>2, ks = rem&3;
    int mg = jmt*16+m, h = ks*32+kl;
    if (mg<100 && h<100) v = Wmsg[(mg*100+h)*4 + t];
    AFhi[slot] = f2bf(v);
  } else if (blk < 280){
    int bb = blk-112, mat = bb/28, rem = bb%28, jmt = rem>>2, ks = rem&3;
    int mg = jmt*16+m, k = ks*32+kl;
    if (mg<100 && k<100)
      v = (mat<3) ? Wih[(mat*100+mg)*100+k] : Whh[((mat-3)*100+mg)*100+k];
    AFhi[slot] = f2bf(v);
  } else if (blk < 315){
    int bb = blk-280, jmt = bb/5, ks = bb%5;
    int mg = jmt*16+m, k = ks*32+kl;
    if (mg<100 && k<140) v = Wg[k*100+mg];
    short hi,lo; bsplit(v,hi,lo);
    AFhi[slot] = hi;
    AFlo[(size_t)(blk-280)*512 + r] = lo;
  } else {
    int bb = blk-315, jmt = bb>>2, ks = bb&3;
    int mg = jmt*16+m, k = ks*32+kl;
    if (mg<100 && k<100) v = We[k*100+mg];
    short hi,lo; bsplit(v,hi,lo);
    AFhi[slot] = hi;
    AFlo[(size_t)(blk-280)*512 + r] = lo;
  }
}

// ---------------------------------------------------------------------------
// Fused MPNN, Z-reassociated messages. 14 tile-tasks (jmt<7 x nt<2), 1/wave.
// 2 barriers/pass:
//  R0: [Z_t = Wmsg_t@H^T (32 MFMA) -> per-wave LDS transpose (no barrier) ->
//       Xm += Z_t@A_t^T (4 MFMA) + hh gates (12 MFMA, B=XcH shared)]   bar
//  R1: [ih gates (12 MFMA, B=XmH) + GRU elementwise (reg h-state)]     bar
// vs old: Y-agg barrier gone, XcT gone (no b16 scatter), XyH gone.
// A-traffic back to factored 40KB/wave/pass (msg 16 + hh 12 + ih 12 blocks).
// Aw stride padded to 40 shorts: b128 reads 2-way (free) instead of 8-way.
// ---------------------------------------------------------------------------
__global__ __launch_bounds__(TB, 4) void mpnn_mfma(
    const float* __restrict__ nodes, const float* __restrict__ edges,
    const short* __restrict__ AFhi, const short* __restrict__ AFlo,
    const float* __restrict__ b_ih, const float* __restrict__ b_hh,
    const float* __restrict__ bg, const float* __restrict__ be,
    const float* __restrict__ Wo, const float* __restrict__ bo,
    float* __restrict__ out){
  const int b = blockIdx.x;
  const int tid = threadIdx.x;
  const int lane = tid & 63;
  const int w = tid >> 6;

  __shared__ short XcH[32*XCS];                   // cat: h | nodes(100..139) | 0
  __shared__ short XmH[32*XMS];                   // messages^T (bf16) [n][m]
  __shared__ short Aw[4][32*AWS];                 // adjacency [t][n][g] (bf16)
  __shared__ short Zs[14*16*ZSP];                 // per-wave Z transpose scratch
  __shared__ float sh_ge[H_];
  __shared__ float sh_part[4][OUT_];              // Wo-tail partials
  __shared__ int   sh_msk[N_];                    // node-has-edges mask

  // ---- zero LDS (rows never written later must be 0) -----------------------
  for (int i=tid;i<(32*XCS)/2;i+=TB){ ((int*)XcH)[i]=0; }
  for (int i=tid;i<(32*XMS)/2;i+=TB){ ((int*)XmH)[i]=0; }
  if (tid < H_) sh_ge[tid]=0.0f;
  __syncthreads();

  // ---- edge staging: adjacency planes + ballot mask (tid == (n,g), TB==N*N)
  {
    int n = tid>>5, g = tid&31;
    const float4 ev = *(const float4*)(edges + (((size_t)b*N_+n)*N_+g)*4);
    float adj = ev.x+ev.y+ev.z+ev.w;                 // one-hot sums, >=0
    unsigned long long bal = __ballot(adj != 0.0f);  // wave covers rows 2w,2w+1
    if (lane == 0)  sh_msk[n] = ((int)(bal & 0xFFFFFFFFull)) != 0;
    if (lane == 32) sh_msk[n] = ((int)(bal >> 32)) != 0;
    Aw[0][n*AWS+g] = f2bf(ev.x);
    Aw[1][n*AWS+g] = f2bf(ev.y);
    Aw[2][n*AWS+g] = f2bf(ev.z);
    Aw[3][n*AWS+g] = f2bf(ev.w);
  }
  for (int p=tid; p<N_*F_; p+=TB){              // grid-stride: 1280 > TB
    int n = p/F_, f = p%F_;
    float x = nodes[((size_t)b*N_+n)*F_ + f];
    short hi = f2bf(x);
    XcH[n*XCS+f]=hi;                            // h init rows 0..39
    XcH[n*XCS+100+f]=hi;                        // cat-tail rows 100..139
  }

  const int jmt = w>>1, nt = w&1;               // task (w<14)
  const bool task = (w < 14);
  const int nrow = nt*16 + (lane&15);           // this lane's B-row (node)
  const int boff = (lane>>4)*8;                 // this lane's k-offset in frag
  const int rowbase = jmt*16 + (lane>>4)*4;     // this lane's 4 output rows
  const int zb = w*16*ZSP;                      // per-wave Z scratch base
  const int zcol = lane&15;                     // Z write col (g-local)
  const int zrow = (lane>>4)*4;                 // Z write row base (j-local)

  // ---- per-lane fp32 GRU state (pass-invariant cell ownership) -------------
  float hst[4] = {0.f,0.f,0.f,0.f};
  if (task){
#pragma unroll
    for (int r=0;r<4;++r){
      int row = rowbase + r;
      if (row < F_) hst[r] = nodes[((size_t)b*N_+nrow)*F_ + row];
    }
  }
  __syncthreads();

  for (int pass=0; pass<3; ++pass){
    // ---- region 0: hh gates + Z-stage + Xm aggregation ---------------------
    f32x4 Ch0=(f32x4)0.0f, Ch1=(f32x4)0.0f, Ch2=(f32x4)0.0f;
    if (task){
      {  // hh gates: B = XcH rows (this nt half), A from global
        const short* pb = XcH + nrow*XCS + boff;
        bf16x8 b0 = *(const bf16x8*)(pb);
        bf16x8 b1 = *(const bf16x8*)(pb+32);
        bf16x8 b2 = *(const bf16x8*)(pb+64);
        bf16x8 b3 = *(const bf16x8*)(pb+96);
        const short* pa = AFhi + ((size_t)(112 + 3*28 + jmt*4))*512 + lane*8;
        {
          bf16x8 a0=*(const bf16x8*)(pa),      a1=*(const bf16x8*)(pa+512);
          bf16x8 a2=*(const bf16x8*)(pa+1024), a3=*(const bf16x8*)(pa+1536);
          Ch0 = MFMA(a0,b0,Ch0); Ch0 = MFMA(a1,b1,Ch0);
          Ch0 = MFMA(a2,b2,Ch0); Ch0 = MFMA(a3,b3,Ch0);
        }
        pa += 28*512;
        {
          bf16x8 a0=*(const bf16x8*)(pa),      a1=*(const bf16x8*)(pa+512);
          bf16x8 a2=*(const bf16x8*)(pa+1024), a3=*(const bf16x8*)(pa+1536);
          Ch1 = MFMA(a0,b0,Ch1); Ch1 = MFMA(a1,b1,Ch1);
          Ch1 = MFMA(a2,b2,Ch1); Ch1 = MFMA(a3,b3,Ch1);
        }
        pa += 28*512;
        {
          bf16x8 a0=*(const bf16x8*)(pa),      a1=*(const bf16x8*)(pa+512);
          bf16x8 a2=*(const bf16x8*)(pa+1024), a3=*(const bf16x8*)(pa+1536);
          Ch2 = MFMA(a0,b0,Ch2); Ch2 = MFMA(a1,b1,Ch2);
          Ch2 = MFMA(a2,b2,Ch2); Ch2 = MFMA(a3,b3,Ch2);
        }
      }
      {  // msg path: per t: Z_t = Wmsg_t @ H^T (both g-halves), transpose via
         // per-wave scratch (same-wave produce/consume, no barrier), then
         // Xm += Z_t @ A_t^T (B = padded adjacency).
        f32x4 Cm=(f32x4)0.0f;
#pragma unroll 1
        for (int t=0;t<4;++t){
          const short* pa = AFhi + ((size_t)(t*28 + jmt*4))*512 + lane*8;
          bf16x8 a0 = *(const bf16x8*)(pa);
          bf16x8 a1 = *(const bf16x8*)(pa+512);
          bf16x8 a2 = *(const bf16x8*)(pa+1024);
          bf16x8 a3 = *(const bf16x8*)(pa+1536);
          const short* pg0 = XcH + (lane&15)*XCS + boff;       // g rows 0..15
          const short* pg1 = pg0 + 16*XCS;                     // g rows 16..31
          f32x4 Z0=(f32x4)0.0f, Z1=(f32x4)0.0f;
          Z0 = MFMA(a0, *(const bf16x8*)(pg0),    Z0);
          Z0 = MFMA(a1, *(const bf16x8*)(pg0+32), Z0);
          Z0 = MFMA(a2, *(const bf16x8*)(pg0+64), Z0);
          Z0 = MFMA(a3, *(const bf16x8*)(pg0+96), Z0);
          Z1 = MFMA(a0, *(const bf16x8*)(pg1),    Z1);
          Z1 = MFMA(a1, *(const bf16x8*)(pg1+32), Z1);
          Z1 = MFMA(a2, *(const bf16x8*)(pg1+64), Z1);
          Z1 = MFMA(a3, *(const bf16x8*)(pg1+96), Z1);
#pragma unroll
          for (int r=0;r<4;++r){                 // D: row=j-local, col=g-local
            Zs[zb + (zrow+r)*ZSP + zcol]      = f2bf(Z0[r]);
            Zs[zb + (zrow+r)*ZSP + zcol + 16] = f2bf(Z1[r]);
          }
          bf16x8 az = *(const bf16x8*)&Zs[zb + (lane&15)*ZSP + boff];
          bf16x8 bt = *(const bf16x8*)&Aw[t][nrow*AWS + boff];
          Cm = MFMA(az, bt, Cm);
        }
        if (rowbase < 100){                      // quads never straddle 100
          short4 pk;
          pk.x = f2bf(Cm[0]); pk.y = f2bf(Cm[1]);
          pk.z = f2bf(Cm[2]); pk.w = f2bf(Cm[3]);
          *(short4*)&XmH[nrow*XMS + rowbase] = pk;
        }
      }
    }
    __syncthreads();
    // ---- region 1: ih gates (B=XmH shared) + GRU elementwise (reg state) ---
    if (task){
      f32x4 Ci0=(f32x4)0.0f, Ci1=(f32x4)0.0f, Ci2=(f32x4)0.0f;
      {
        const short* pb = XmH + nrow*XMS + boff;
        bf16x8 b0 = *(const bf16x8*)(pb);
        bf16x8 b1 = *(const bf16x8*)(pb+32);
        bf16x8 b2 = *(const bf16x8*)(pb+64);
        bf16x8 b3 = *(const bf16x8*)(pb+96);
        const short* pa = AFhi + ((size_t)(112 + jmt*4))*512 + lane*8;
        {
          bf16x8 a0=*(const bf16x8*)(pa),      a1=*(const bf16x8*)(pa+512);
          bf16x8 a2=*(const bf16x8*)(pa+1024), a3=*(const bf16x8*)(pa+1536);
          Ci0 = MFMA(a0,b0,Ci0); Ci0 = MFMA(a1,b1,Ci0);
          Ci0 = MFMA(a2,b2,Ci0); Ci0 = MFMA(a3,b3,Ci0);
        }
        pa += 28*512;
        {
          bf16x8 a0=*(const bf16x8*)(pa),      a1=*(const bf16x8*)(pa+512);
          bf16x8 a2=*(const bf16x8*)(pa+1024), a3=*(const bf16x8*)(pa+1536);
          Ci1 = MFMA(a0,b0,Ci1); Ci1 = MFMA(a1,b1,Ci1);
          Ci1 = MFMA(a2,b2,Ci1); Ci1 = MFMA(a3,b3,Ci1);
        }
        pa += 28*512;
        {
          bf16x8 a0=*(const bf16x8*)(pa),      a1=*(const bf16x8*)(pa+512);
          bf16x8 a2=*(const bf16x8*)(pa+1024), a3=*(const bf16x8*)(pa+1536);
          Ci2 = MFMA(a0,b0,Ci2); Ci2 = MFMA(a1,b1,Ci2);
          Ci2 = MFMA(a2,b2,Ci2); Ci2 = MFMA(a3,b3,Ci2);
        }
      }
      if (rowbase < 100){
        bool msk = sh_msk[nrow] != 0;
        short4 pk;
#pragma unroll
        for (int r=0;r<4;++r){
          int row = rowbase + r;
          float ho = hst[r];
          float rr = sigmoidf_(Ci0[r]+Ch0[r] + b_ih[row]     + b_hh[row]);
          float zz = sigmoidf_(Ci1[r]+Ch1[r] + b_ih[100+row] + b_hh[100+row]);
          float nn = tanhf_(Ci2[r] + b_ih[200+row] + rr*(Ch2[r] + b_hh[200+row]));
          float hnew = (1.0f-zz)*nn + zz*ho;
          if (!msk) hnew = ho;
          hst[r] = hnew;
          ((short*)&pk)[r] = f2bf(hnew);
        }
        *(short4*)&XcH[nrow*XCS + rowbase] = pk;
      }
    }
    __syncthreads();
  }

  // ---- readout: gate/emb GEMMs (A hi+lo, B=XcH shared), masked sum ---------
  f32x4 Cg=(f32x4)0.0f, Ce=(f32x4)0.0f;
  if (task){
    const short* pb = XcH + nrow*XCS + boff;
    bf16x8 b0 = *(const bf16x8*)(pb);
    bf16x8 b1 = *(const bf16x8*)(pb+32);
    bf16x8 b2 = *(const bf16x8*)(pb+64);
    bf16x8 b3 = *(const bf16x8*)(pb+96);
    bf16x8 b4 = *(const bf16x8*)(pb+128);
    {  // Wg: blocks 280+jmt*5 .. +4 (hi) and same-idx lo
      const short* ph = AFhi + ((size_t)(280 + jmt*5))*512 + lane*8;
      const short* pl = AFlo + ((size_t)(jmt*5))*512 + lane*8;
      Cg = MFMA(*(const bf16x8*)(ph),      b0, Cg);
      Cg = MFMA(*(const bf16x8*)(pl),      b0, Cg);
      Cg = MFMA(*(const bf16x8*)(ph+512),  b1, Cg);
      Cg = MFMA(*(const bf16x8*)(pl+512),  b1, Cg);
      Cg = MFMA(*(const bf16x8*)(ph+1024), b2, Cg);
      Cg = MFMA(*(const bf16x8*)(pl+1024), b2, Cg);
      Cg = MFMA(*(const bf16x8*)(ph+1536), b3, Cg);
      Cg = MFMA(*(const bf16x8*)(pl+1536), b3, Cg);
      Cg = MFMA(*(const bf16x8*)(ph+2048), b4, Cg);
      Cg = MFMA(*(const bf16x8*)(pl+2048), b4, Cg);
    }
    {  // We: blocks 315+jmt*4 .. +3 (hi), lo at (blk-280)
      const short* ph = AFhi + ((size_t)(315 + jmt*4))*512 + lane*8;
      const short* pl = AFlo + ((size_t)(35 + jmt*4))*512 + lane*8;
      Ce = MFMA(*(const bf16x8*)(ph),      b0, Ce);
      Ce = MFMA(*(const bf16x8*)(pl),      b0, Ce);
      Ce = MFMA(*(const bf16x8*)(ph+512),  b1, Ce);
      Ce = MFMA(*(const bf16x8*)(pl+512),  b1, Ce);
      Ce = MFMA(*(const bf16x8*)(ph+1024), b2, Ce);
      Ce = MFMA(*(const bf16x8*)(pl+1024), b2, Ce);
      Ce = MFMA(*(const bf16x8*)(ph+1536), b3, Ce);
      Ce = MFMA(*(const bf16x8*)(pl+1536), b3, Ce);
    }
    bool msk = sh_msk[nrow] != 0;
#pragma unroll
    for (int r=0;r<4;++r){
      int row = rowbase + r;
      float v = 0.0f;
      if (row<100){
        float gate = sigmoidf_(Cg[r] + bg[row]);
        float emb  = gate*(Ce[r] + be[row]);
        v = msk ? emb : 0.0f;
      }
      v += __shfl_xor(v, 1);                   // reduce across 16 cols
      v += __shfl_xor(v, 2);
      v += __shfl_xor(v, 4);
      v += __shfl_xor(v, 8);
      if (row<100 && (lane&15)==0) atomicAdd(&sh_ge[row], v);
    }
  }
  __syncthreads();
  // ---- out = graph_emb @ Wo + bo : 512 threads, 4 k-chunks of 25 -----------
  if (tid < 512){
    int o = tid & 127, q = tid >> 7;           // lanes consecutive in o -> coalesced
    float s = 0.0f;
    int k0 = 25*q;
#pragma unroll 5
    for (int k=k0; k<k0+25; ++k) s += sh_ge[k]*Wo[k*OUT_+o];
    sh_part[q][o] = s;
  }
  __syncthreads();
  if (tid < OUT_){
    out[(size_t)b*OUT_ + tid] = bo[tid] + sh_part[0][tid] + sh_part[1][tid]
                              + sh_part[2][tid] + sh_part[3][tid];
  }
}

extern "C" void kernel_launch(void* const* d_in, const int* in_sizes, int n_in,
                              void* d_out, int out_size, void* d_ws, size_t ws_size,
                              hipStream_t stream){
  const float* nodes = (const float*)d_in[0];
  const float* edges = (const float*)d_in[1];
  const float* W_msg = (const float*)d_in[2];
  const float* W_ih  = (const float*)d_in[3];
  const float* W_hh  = (const float*)d_in[4];
  const float* b_ih  = (const float*)d_in[5];
  const float* b_hh  = (const float*)d_in[6];
  const float* Wg    = (const float*)d_in[7];
  const float* bg    = (const float*)d_in[8];
  const float* We    = (const float*)d_in[9];
  const float* be    = (const float*)d_in[10];
  const float* Wo    = (const float*)d_in[11];
  const float* bo    = (const float*)d_in[12];

  short* AFhi = (short*)d_ws;                        // 343*512 shorts = 343 KB
  short* AFlo = AFhi + (size_t)NBLK*512;             //  63*512 shorts =  63 KB

  prep_frags4<<<(NBLK*512 + 255)/256, 256, 0, stream>>>(W_msg, W_ih, W_hh, Wg, We,
                                                        AFhi, AFlo);
  mpnn_mfma<<<B_, TB, 0, stream>>>(nodes, edges, AFhi, AFlo, b_ih, b_hh, bg, be,
                                   Wo, bo, (float*)d_out);
}

// Round 4
// 108.908 us; speedup vs baseline: 1.2620x; 1.1295x over previous
//
#include <hip/hip_runtime.h>
#include <cstddef>
#include <cstdint>

// B=256, N=32, F=40, H=M=100, EF=4, OUT=128, 3 passes.
#define B_   256
#define N_   32
#define F_   40
#define H_   100
#define OUT_ 128
#define TB   512          // 8 waves/block, 1 block/CU, 2 waves/SIMD -> VGPR<=256
#define XCS  168          // XcH row stride (shorts), 16B-multiple
#define XMS  136          // XmH row stride (shorts), 16B-multiple
#define AWS  40           // Aw row stride (shorts): padded (no 8-way conflict)
#define ZSP  40           // Zs row stride (shorts)
#define NBLK 343          // AFhi blocks: 112 msg + 168 GRU + 35 Wg + 28 We
#define NLO  63           // AFlo blocks (readout lo)

using bf16x8 = __attribute__((ext_vector_type(8))) short;   // 8 bf16 (4 VGPRs)
using f32x4  = __attribute__((ext_vector_type(4))) float;   // MFMA C/D

#define MFMA(a,b,c) __builtin_amdgcn_mfma_f32_16x16x32_bf16((a),(b),(c),0,0,0)

__device__ __forceinline__ float sigmoidf_(float x){ return 1.0f/(1.0f+__expf(-x)); }
__device__ __forceinline__ float tanhf_(float x){           // fast tanh via __expf
  float e = __expf(2.0f*x);
  return 1.0f - 2.0f/(e+1.0f);
}
__device__ __forceinline__ float bf2f(short s){ return __uint_as_float(((uint32_t)(uint16_t)s)<<16); }
__device__ __forceinline__ short f2bf(float x){             // round-to-nearest-even
  uint32_t u = __float_as_uint(x);
  return (short)((u + 0x7FFFu + ((u>>16)&1u))>>16);
}
__device__ __forceinline__ void bsplit(float x, short& hi, short& lo){
  hi = f2bf(x);
  lo = f2bf(x - bf2f(hi));
}

// ---------------------------------------------------------------------------
// Weight pre-pack v4 (proven trivial-copy layout): SLOT-indexed, OOR slots 0.
//   [0,112)   W_msg : t*28 + jmt*4 + ks        A[m][h]=W_msg[m, h, t]
//   [112,280) GRU   : 112+mat*28+jmt*4+ks      mat: ihr,ihz,ihn,hhr,hhz,hhn
//   [280,315) Wg^T  : 280+jmt*5+ks (K=140)     A[j][k]=Wg[k, j]  (hi+lo)
//   [315,343) We^T  : 315+jmt*4+ks             A[j][k]=We[k, j]  (hi+lo)
// ---------------------------------------------------------------------------
__global__ void prep_frags4(const float* __restrict__ Wmsg,
                            const float* __restrict__ Wih,
                            const float* __restrict__ Whh,
                            const float* __restrict__ Wg,
                            const float* __restrict__ We,
                            short* __restrict__ AFhi,
                            short* __restrict__ AFlo){
  int slot = blockIdx.x*blockDim.x + threadIdx.x;
  if (slot >= NBLK*512) return;
  int blk = slot>>9, r = slot&511, lane = r>>3, jj = r&7;
  int m = lane&15, q = lane>>4, kl = q*8+jj;
  float v = 0.0f;
  if (blk < 112){
    int t = blk/28, rem = blk%28, jmt = rem>>2, ks = rem&3;
    int mg = jmt*16+m, h = ks*32+kl;
    if (mg<100 && h<100) v = Wmsg[(mg*100+h)*4 + t];
    AFhi[slot] = f2bf(v);
  } else if (blk < 280){
    int bb = blk-112, mat = bb/28, rem = bb%28, jmt = rem>>2, ks = rem&3;
    int mg = jmt*16+m, k = ks*32+kl;
    if (mg<100 && k<100)
      v = (mat<3) ? Wih[(mat*100+mg)*100+k] : Whh[((mat-3)*100+mg)*100+k];
    AFhi[slot] = f2bf(v);
  } else if (blk < 315){
    int bb = blk-280, jmt = bb/5, ks = bb%5;
    int mg = jmt*16+m, k = ks*32+kl;
    if (mg<100 && k<140) v = Wg[k*100+mg];
    short hi,lo; bsplit(v,hi,lo);
    AFhi[slot] = hi;
    AFlo[(size_t)(blk-280)*512 + r] = lo;
  } else {
    int bb = blk-315, jmt = bb>>2, ks = bb&3;
    int mg = jmt*16+m, k = ks*32+kl;
    if (mg<100 && k<100) v = We[k*100+mg];
    short hi,lo; bsplit(v,hi,lo);
    AFhi[slot] = hi;
    AFlo[(size_t)(blk-280)*512 + r] = lo;
  }
}

// ---------------------------------------------------------------------------
// Fused MPNN, weight-stationary. 8 waves; wave w = jmt tile (w<7 active),
// BOTH node halves per wave. GRU A-frags (ih+hh, 96 VGPR) + biases live in
// registers across all 3 passes -> pass loop has only 16 msg A-frag global
// loads/wave/pass. Z computed once per jmt (nt-independent), az reused for
// both halves. 2 barriers/pass.
// ---------------------------------------------------------------------------
__global__ __launch_bounds__(TB, 2) void mpnn_mfma(
    const float* __restrict__ nodes, const float* __restrict__ edges,
    const short* __restrict__ AFhi, const short* __restrict__ AFlo,
    const float* __restrict__ b_ih, const float* __restrict__ b_hh,
    const float* __restrict__ bg, const float* __restrict__ be,
    const float* __restrict__ Wo, const float* __restrict__ bo,
    float* __restrict__ out){
  const int b = blockIdx.x;
  const int tid = threadIdx.x;
  const int lane = tid & 63;
  const int w = tid >> 6;                         // 0..7

  __shared__ short XcH[32*XCS];                   // cat: h | nodes(100..139) | 0
  __shared__ short XmH[32*XMS];                   // messages (bf16) [n][m]
  __shared__ short Aw[4][32*AWS];                 // adjacency [t][n][g] (bf16)
  __shared__ short Zs[7*4*16*ZSP];                // [wave][t][16][ZSP] Z scratch
  __shared__ float sh_ge[H_];
  __shared__ float sh_part[4][OUT_];              // Wo-tail partials
  __shared__ int   sh_msk[N_];                    // node-has-edges mask

  // ---- zero LDS (rows never written later must be 0) -----------------------
  for (int i=tid;i<(32*XCS)/2;i+=TB){ ((int*)XcH)[i]=0; }
  for (int i=tid;i<(32*XMS)/2;i+=TB){ ((int*)XmH)[i]=0; }
  if (tid < H_) sh_ge[tid]=0.0f;
  __syncthreads();

  // ---- edge staging: adjacency planes + ballot mask ------------------------
  for (int e=tid; e<N_*N_; e+=TB){
    int n = e>>5, g = e&31;
    const float4 ev = *(const float4*)(edges + (((size_t)b*N_+n)*N_+g)*4);
    float adj = ev.x+ev.y+ev.z+ev.w;                 // one-hot sums, >=0
    unsigned long long bal = __ballot(adj != 0.0f);  // wave covers 2 n-rows
    if (lane == 0)  sh_msk[n] = ((int)(bal & 0xFFFFFFFFull)) != 0;
    if (lane == 32) sh_msk[n] = ((int)(bal >> 32)) != 0;
    Aw[0][n*AWS+g] = f2bf(ev.x);
    Aw[1][n*AWS+g] = f2bf(ev.y);
    Aw[2][n*AWS+g] = f2bf(ev.z);
    Aw[3][n*AWS+g] = f2bf(ev.w);
  }
  for (int p=tid; p<N_*F_; p+=TB){
    int n = p/F_, f = p%F_;
    float x = nodes[((size_t)b*N_+n)*F_ + f];
    short hi = f2bf(x);
    XcH[n*XCS+f]=hi;                            // h init rows 0..39
    XcH[n*XCS+100+f]=hi;                        // cat-tail rows 100..139
  }

  const int jmt = w;                            // one jmt per wave (w<7)
  const bool task = (w < 7);
  const int c16 = lane & 15;
  const int q   = lane >> 4;
  const int boff = q*8;                         // k-offset in B/A frags
  const int rowbase = jmt*16 + q*4;             // this lane's 4 output rows
  const int n0 = c16, n1 = 16 + c16;            // both node halves

  // ---- register-resident GRU A-frags (ih mat 0..2, hh mat 0..2) ------------
  bf16x8 Ai[3][4], Ah[3][4];
  if (task){
#pragma unroll
    for (int mat=0; mat<3; ++mat){
#pragma unroll
      for (int ks=0; ks<4; ++ks){
        Ai[mat][ks] = *(const bf16x8*)(AFhi + ((size_t)(112 + mat*28 + jmt*4 + ks))*512 + lane*8);
        Ah[mat][ks] = *(const bf16x8*)(AFhi + ((size_t)(112 + (3+mat)*28 + jmt*4 + ks))*512 + lane*8);
      }
    }
  }
  // ---- register-resident GRU biases (guarded: rows >=100 are dead) ---------
  float bi0[4],bi1[4],bi2[4],bh0[4],bh1[4],bh2[4];
  if (task){
#pragma unroll
    for (int r=0;r<4;++r){
      int row = rowbase + r;
      bool ok = row < 100;
      bi0[r] = ok ? b_ih[row]       : 0.0f;
      bi1[r] = ok ? b_ih[100+row]   : 0.0f;
      bi2[r] = ok ? b_ih[200+row]   : 0.0f;
      bh0[r] = ok ? b_hh[row]       : 0.0f;
      bh1[r] = ok ? b_hh[100+row]   : 0.0f;
      bh2[r] = ok ? b_hh[200+row]   : 0.0f;
    }
  }

  // ---- per-lane fp32 GRU state, both halves --------------------------------
  float hst0[4]={0.f,0.f,0.f,0.f}, hst1[4]={0.f,0.f,0.f,0.f};
  if (task){
#pragma unroll
    for (int r=0;r<4;++r){
      int row = rowbase + r;
      if (row < F_){
        hst0[r] = nodes[((size_t)b*N_+n0)*F_ + row];
        hst1[r] = nodes[((size_t)b*N_+n1)*F_ + row];
      }
    }
  }
  __syncthreads();

  for (int pass=0; pass<3; ++pass){
    f32x4 Chh[3][2];
#pragma unroll
    for (int m3=0;m3<3;++m3){ Chh[m3][0]=(f32x4)0.0f; Chh[m3][1]=(f32x4)0.0f; }
    // ---- region 0: Z (once per jmt) -> Xm agg (both halves) + hh gates -----
    if (task){
      // shared B-frags: XcH rows = nodes (serve Z's H^T AND hh's per-half B)
      const short* pb0 = XcH + n0*XCS + boff;
      const short* pb1 = XcH + n1*XCS + boff;
      bf16x8 x0[4], x1[4];
#pragma unroll
      for (int ks=0;ks<4;++ks){
        x0[ks] = *(const bf16x8*)(pb0 + ks*32);
        x1[ks] = *(const bf16x8*)(pb1 + ks*32);
      }
      // Z + aggregation, t in pairs to bound register pressure
      f32x4 Cm0=(f32x4)0.0f, Cm1=(f32x4)0.0f;
#pragma unroll
      for (int th=0; th<2; ++th){
        f32x4 Za[2][2];
#pragma unroll
        for (int u=0;u<2;++u){
          int t = th*2+u;
          const short* pa = AFhi + ((size_t)(t*28 + jmt*4))*512 + lane*8;
          bf16x8 a0 = *(const bf16x8*)(pa);
          bf16x8 a1 = *(const bf16x8*)(pa+512);
          bf16x8 a2 = *(const bf16x8*)(pa+1024);
          bf16x8 a3 = *(const bf16x8*)(pa+1536);
          Za[u][0]=(f32x4)0.0f; Za[u][1]=(f32x4)0.0f;
          Za[u][0]=MFMA(a0,x0[0],Za[u][0]); Za[u][0]=MFMA(a1,x0[1],Za[u][0]);
          Za[u][0]=MFMA(a2,x0[2],Za[u][0]); Za[u][0]=MFMA(a3,x0[3],Za[u][0]);
          Za[u][1]=MFMA(a0,x1[0],Za[u][1]); Za[u][1]=MFMA(a1,x1[1],Za[u][1]);
          Za[u][1]=MFMA(a2,x1[2],Za[u][1]); Za[u][1]=MFMA(a3,x1[3],Za[u][1]);
        }
#pragma unroll
        for (int u=0;u<2;++u){
          int t = th*2+u;
          int zb = (w*4+t)*16*ZSP;
#pragma unroll
          for (int r=0;r<4;++r){                 // D: row=j-local, col=g
            Zs[zb + (q*4+r)*ZSP + c16]      = f2bf(Za[u][0][r]);
            Zs[zb + (q*4+r)*ZSP + c16 + 16] = f2bf(Za[u][1][r]);
          }
        }
#pragma unroll
        for (int u=0;u<2;++u){
          int t = th*2+u;
          int zb = (w*4+t)*16*ZSP;
          bf16x8 az  = *(const bf16x8*)&Zs[zb + c16*ZSP + boff];
          bf16x8 bt0 = *(const bf16x8*)&Aw[t][n0*AWS + boff];
          bf16x8 bt1 = *(const bf16x8*)&Aw[t][n1*AWS + boff];
          Cm0 = MFMA(az, bt0, Cm0);
          Cm1 = MFMA(az, bt1, Cm1);
        }
      }
      if (rowbase < 100){                        // quads never straddle 100
        short4 pk0, pk1;
        pk0.x=f2bf(Cm0[0]); pk0.y=f2bf(Cm0[1]); pk0.z=f2bf(Cm0[2]); pk0.w=f2bf(Cm0[3]);
        pk1.x=f2bf(Cm1[0]); pk1.y=f2bf(Cm1[1]); pk1.z=f2bf(Cm1[2]); pk1.w=f2bf(Cm1[3]);
        *(short4*)&XmH[n0*XMS + rowbase] = pk0;
        *(short4*)&XmH[n1*XMS + rowbase] = pk1;
      }
      // hh gates, both halves, resident A
#pragma unroll
      for (int m3=0;m3<3;++m3){
#pragma unroll
        for (int ks=0;ks<4;++ks){
          Chh[m3][0] = MFMA(Ah[m3][ks], x0[ks], Chh[m3][0]);
          Chh[m3][1] = MFMA(Ah[m3][ks], x1[ks], Chh[m3][1]);
        }
      }
    }
    __syncthreads();
    // ---- region 1: ih gates (B=XmH, both halves) + GRU (reg state) ---------
    if (task){
      const short* pm0 = XmH + n0*XMS + boff;
      const short* pm1 = XmH + n1*XMS + boff;
      bf16x8 m0f[4], m1f[4];
#pragma unroll
      for (int ks=0;ks<4;++ks){
        m0f[ks] = *(const bf16x8*)(pm0 + ks*32);
        m1f[ks] = *(const bf16x8*)(pm1 + ks*32);
      }
      f32x4 Ci[3][2];
#pragma unroll
      for (int m3=0;m3<3;++m3){ Ci[m3][0]=(f32x4)0.0f; Ci[m3][1]=(f32x4)0.0f; }
#pragma unroll
      for (int m3=0;m3<3;++m3){
#pragma unroll
        for (int ks=0;ks<4;++ks){
          Ci[m3][0] = MFMA(Ai[m3][ks], m0f[ks], Ci[m3][0]);
          Ci[m3][1] = MFMA(Ai[m3][ks], m1f[ks], Ci[m3][1]);
        }
      }
      if (rowbase < 100){
        bool k0 = sh_msk[n0] != 0, k1 = sh_msk[n1] != 0;
        short4 pk0, pk1;
#pragma unroll
        for (int r=0;r<4;++r){
          {
            float ho = hst0[r];
            float rr = sigmoidf_(Ci[0][0][r]+Chh[0][0][r] + bi0[r] + bh0[r]);
            float zz = sigmoidf_(Ci[1][0][r]+Chh[1][0][r] + bi1[r] + bh1[r]);
            float nn = tanhf_(Ci[2][0][r] + bi2[r] + rr*(Chh[2][0][r] + bh2[r]));
            float hnew = (1.0f-zz)*nn + zz*ho;
            if (!k0) hnew = ho;
            hst0[r] = hnew;
            ((short*)&pk0)[r] = f2bf(hnew);
          }
          {
            float ho = hst1[r];
            float rr = sigmoidf_(Ci[0][1][r]+Chh[0][1][r] + bi0[r] + bh0[r]);
            float zz = sigmoidf_(Ci[1][1][r]+Chh[1][1][r] + bi1[r] + bh1[r]);
            float nn = tanhf_(Ci[2][1][r] + bi2[r] + rr*(Chh[2][1][r] + bh2[r]));
            float hnew = (1.0f-zz)*nn + zz*ho;
            if (!k1) hnew = ho;
            hst1[r] = hnew;
            ((short*)&pk1)[r] = f2bf(hnew);
          }
        }
        *(short4*)&XcH[n0*XCS + rowbase] = pk0;
        *(short4*)&XcH[n1*XCS + rowbase] = pk1;
      }
    }
    __syncthreads();
  }

  // ---- readout: gate/emb GEMMs (A hi+lo), both halves, masked sum ----------
  if (task){
    const short* pb0 = XcH + n0*XCS + boff;
    const short* pb1 = XcH + n1*XCS + boff;
    bf16x8 rb0[5], rb1[5];
#pragma unroll
    for (int ks=0;ks<5;++ks){
      rb0[ks] = *(const bf16x8*)(pb0 + ks*32);
      rb1[ks] = *(const bf16x8*)(pb1 + ks*32);
    }
    f32x4 Cg0=(f32x4)0.0f, Cg1=(f32x4)0.0f, Ce0=(f32x4)0.0f, Ce1=(f32x4)0.0f;
    {  // Wg: blocks 280+jmt*5 .. +4 (hi) and same-idx lo, K=140
      const short* ph = AFhi + ((size_t)(280 + jmt*5))*512 + lane*8;
      const short* pl = AFlo + ((size_t)(jmt*5))*512 + lane*8;
#pragma unroll
      for (int ks=0;ks<5;++ks){
        bf16x8 ah = *(const bf16x8*)(ph + ks*512);
        bf16x8 al = *(const bf16x8*)(pl + ks*512);
        Cg0 = MFMA(ah, rb0[ks], Cg0); Cg0 = MFMA(al, rb0[ks], Cg0);
        Cg1 = MFMA(ah, rb1[ks], Cg1); Cg1 = MFMA(al, rb1[ks], Cg1);
      }
    }
    {  // We: blocks 315+jmt*4 .. +3 (hi), lo at (blk-280)
      const short* ph = AFhi + ((size_t)(315 + jmt*4))*512 + lane*8;
      const short* pl = AFlo + ((size_t)(35 + jmt*4))*512 + lane*8;
#pragma unroll
      for (int ks=0;ks<4;++ks){
        bf16x8 ah = *(const bf16x8*)(ph + ks*512);
        bf16x8 al = *(const bf16x8*)(pl + ks*512);
        Ce0 = MFMA(ah, rb0[ks], Ce0); Ce0 = MFMA(al, rb0[ks], Ce0);
        Ce1 = MFMA(ah, rb1[ks], Ce1); Ce1 = MFMA(al, rb1[ks], Ce1);
      }
    }
    bool k0 = sh_msk[n0] != 0, k1 = sh_msk[n1] != 0;
#pragma unroll
    for (int r=0;r<4;++r){
      int row = rowbase + r;
      float v0 = 0.0f, v1 = 0.0f;
      if (row<100){
        float g0 = sigmoidf_(Cg0[r] + bg[row]);
        float g1 = sigmoidf_(Cg1[r] + bg[row]);
        float e0 = g0*(Ce0[r] + be[row]);
        float e1 = g1*(Ce1[r] + be[row]);
        v0 = k0 ? e0 : 0.0f;
        v1 = k1 ? e1 : 0.0f;
      }
      float v = v0 + v1;                       // halves sum into same graph-emb
      v += __shfl_xor(v, 1);                   // reduce across 16 cols
      v += __shfl_xor(v, 2);
      v += __shfl_xor(v, 4);
      v += __shfl_xor(v, 8);
      if (row<100 && (lane&15)==0) atomicAdd(&sh_ge[row], v);
    }
  }
  __syncthreads();
  // ---- out = graph_emb @ Wo + bo : 512 threads, 4 k-chunks of 25 -----------
  {
    int o = tid & 127, qq = tid >> 7;          // lanes consecutive in o -> coalesced
    float s = 0.0f;
    int k0 = 25*qq;
#pragma unroll 5
    for (int k=k0; k<k0+25; ++k) s += sh_ge[k]*Wo[k*OUT_+o];
    sh_part[qq][o] = s;
  }
  __syncthreads();
  if (tid < OUT_){
    out[(size_t)b*OUT_ + tid] = bo[tid] + sh_part[0][tid] + sh_part[1][tid]
                              + sh_part[2][tid] + sh_part[3][tid];
  }
}

extern "C" void kernel_launch(void* const* d_in, const int* in_sizes, int n_in,
                              void* d_out, int out_size, void* d_ws, size_t ws_size,
                              hipStream_t stream){
  const float* nodes = (const float*)d_in[0];
  const float* edges = (const float*)d_in[1];
  const float* W_msg = (const float*)d_in[2];
  const float* W_ih  = (const float*)d_in[3];
  const float* W_hh  = (const float*)d_in[4];
  const float* b_ih  = (const float*)d_in[5];
  const float* b_hh  = (const float*)d_in[6];
  const float* Wg    = (const float*)d_in[7];
  const float* bg    = (const float*)d_in[8];
  const float* We    = (const float*)d_in[9];
  const float* be    = (const float*)d_in[10];
  const float* Wo    = (const float*)d_in[11];
  const float* bo    = (const float*)d_in[12];

  short* AFhi = (short*)d_ws;                        // 343*512 shorts = 343 KB
  short* AFlo = AFhi + (size_t)NBLK*512;             //  63*512 shorts =  63 KB

  prep_frags4<<<(NBLK*512 + 255)/256, 256, 0, stream>>>(W_msg, W_ih, W_hh, Wg, We,
                                                        AFhi, AFlo);
  mpnn_mfma<<<B_, TB, 0, stream>>>(nodes, edges, AFhi, AFlo, b_ih, b_hh, bg, be,
                                   Wo, bo, (float*)d_out);
}